// Round 1
// baseline (19667.952 us; speedup 1.0000x reference)
//
#include <hip/hip_runtime.h>
#include <cmath>

#define E_EDGES 100000
#define NNODES  10000
#define NGRAPHS 64
#define EMBED   512
#define FF      1024
#define NGAUSS  50
#define KIN     (3 * EMBED)

__device__ __forceinline__ float gelu_tanh(float v) {
    // jax.nn.gelu default (approximate=True): 0.5*x*(1+tanh(sqrt(2/pi)*(x+0.044715x^3)))
    return 0.5f * v * (1.0f + tanhf(0.7978845608028654f * (v + 0.044715f * v * v * v)));
}

// ---------------------------------------------------------------------------
// K1: h1[e][n] = gelu( [x[src[e]] | x[dst[e]] | x[NNODES+e]] @ Win + bin )
// BM=128, BN=128, BK=16, 256 threads, 8x8 microtile.
// ---------------------------------------------------------------------------
__global__ __launch_bounds__(256) void k1_gemm_gelu(
    const float* __restrict__ x, const int* __restrict__ ei,
    const float* __restrict__ Win, const float* __restrict__ bin_,
    float* __restrict__ h1)
{
    __shared__ float As[16][132];   // [k][row], transposed, +4 pad (2-way = free)
    __shared__ float Bs[16][132];   // [k][col]
    __shared__ int lsrc[128], ldst[128];

    const int tid = threadIdx.x;
    const int e0 = blockIdx.x * 128;
    const int n0 = blockIdx.y * 128;

    if (tid < 128) {
        int e = e0 + tid;
        int ec = (e < E_EDGES) ? e : 0;
        lsrc[tid] = ei[ec];
        ldst[tid] = ei[E_EDGES + ec];
    }
    __syncthreads();

    const int ty = tid >> 4, tx = tid & 15;
    const int r0 = ty * 8, c0 = tx * 8;

    float acc[8][8];
#pragma unroll
    for (int i = 0; i < 8; ++i)
#pragma unroll
        for (int j = 0; j < 8; ++j) acc[i][j] = 0.0f;

    for (int k0 = 0; k0 < KIN; k0 += 16) {
        // A gather: 128x16 = 2048 elems; 16 lanes per row -> 64B contiguous segs.
        // k0 is a multiple of 16, so the section branch is uniform per tile.
#pragma unroll
        for (int i = 0; i < 8; ++i) {
            int idx = i * 256 + tid;
            int r = idx >> 4, kk = idx & 15;
            int k = k0 + kk;
            const float* base;
            int col;
            if (k < EMBED)          { base = x + (size_t)lsrc[r] * EMBED; col = k; }
            else if (k < 2 * EMBED) { base = x + (size_t)ldst[r] * EMBED; col = k - EMBED; }
            else {
                int e = e0 + r; int ec = (e < E_EDGES) ? e : 0;
                base = x + (size_t)(NNODES + ec) * EMBED; col = k - 2 * EMBED;
            }
            As[kk][r] = base[col];
        }
        // B: 16x128 via float4, fully coalesced.
#pragma unroll
        for (int i = 0; i < 2; ++i) {
            int f4 = i * 256 + tid;          // 512 float4 total
            int kr = f4 >> 5, c4 = f4 & 31;  // 32 float4 per row
            *(float4*)&Bs[kr][c4 * 4] =
                *(const float4*)&Win[(size_t)(k0 + kr) * FF + n0 + c4 * 4];
        }
        __syncthreads();
#pragma unroll
        for (int kk = 0; kk < 16; ++kk) {
            float4 a0 = *(const float4*)&As[kk][r0];
            float4 a1 = *(const float4*)&As[kk][r0 + 4];
            float4 b0 = *(const float4*)&Bs[kk][c0];
            float4 b1 = *(const float4*)&Bs[kk][c0 + 4];
            float a[8] = {a0.x, a0.y, a0.z, a0.w, a1.x, a1.y, a1.z, a1.w};
            float b[8] = {b0.x, b0.y, b0.z, b0.w, b1.x, b1.y, b1.z, b1.w};
#pragma unroll
            for (int i = 0; i < 8; ++i)
#pragma unroll
                for (int j = 0; j < 8; ++j) acc[i][j] += a[i] * b[j];
        }
        __syncthreads();
    }

#pragma unroll
    for (int i = 0; i < 8; ++i) {
        int e = e0 + r0 + i;
        if (e >= E_EDGES) continue;
        float o[8];
#pragma unroll
        for (int j = 0; j < 8; ++j)
            o[j] = gelu_tanh(acc[i][j] + bin_[n0 + c0 + j]);
        *(float4*)&h1[(size_t)e * FF + n0 + c0]     = make_float4(o[0], o[1], o[2], o[3]);
        *(float4*)&h1[(size_t)e * FF + n0 + c0 + 4] = make_float4(o[4], o[5], o[6], o[7]);
    }
}

// ---------------------------------------------------------------------------
// K2: h1 <- h1 + gelu(h1 @ Wres + bres), in place.
// BM=32 rows/block with the FULL N=1024 (each block owns its rows entirely ->
// no cross-block read/write race for the in-place update). 512 threads, 8x8.
// ---------------------------------------------------------------------------
__global__ __launch_bounds__(512) void k2_resmlp(
    float* __restrict__ h1, const float* __restrict__ Wres,
    const float* __restrict__ bres)
{
    __shared__ float As[8][36];
    __shared__ float Bs[8][FF];

    const int tid = threadIdx.x;
    const int e0 = blockIdx.x * 32;
    const int ty = tid >> 7, tx = tid & 127;
    const int r0 = ty * 8, c0 = tx * 8;

    float acc[8][8];
#pragma unroll
    for (int i = 0; i < 8; ++i)
#pragma unroll
        for (int j = 0; j < 8; ++j) acc[i][j] = 0.0f;

    for (int k0 = 0; k0 < FF; k0 += 8) {
        if (tid < 256) {
            int r = tid >> 3, kk = tid & 7;
            As[kk][r] = h1[(size_t)(e0 + r) * FF + k0 + kk];
        }
#pragma unroll
        for (int i = 0; i < 4; ++i) {
            int f4 = i * 512 + tid;           // 2048 float4 total
            int kr = f4 >> 8, c4 = f4 & 255;  // 256 float4 per row
            *(float4*)&Bs[kr][c4 * 4] =
                *(const float4*)&Wres[(size_t)(k0 + kr) * FF + c4 * 4];
        }
        __syncthreads();
#pragma unroll
        for (int kk = 0; kk < 8; ++kk) {
            float4 a0 = *(const float4*)&As[kk][r0];
            float4 a1 = *(const float4*)&As[kk][r0 + 4];
            float4 b0 = *(const float4*)&Bs[kk][c0];
            float4 b1 = *(const float4*)&Bs[kk][c0 + 4];
            float a[8] = {a0.x, a0.y, a0.z, a0.w, a1.x, a1.y, a1.z, a1.w};
            float b[8] = {b0.x, b0.y, b0.z, b0.w, b1.x, b1.y, b1.z, b1.w};
#pragma unroll
            for (int i = 0; i < 8; ++i)
#pragma unroll
                for (int j = 0; j < 8; ++j) acc[i][j] += a[i] * b[j];
        }
        __syncthreads();
    }

#pragma unroll
    for (int i = 0; i < 8; ++i) {
        size_t row = (size_t)(e0 + r0 + i) * FF + c0;
        float4 o0 = *(const float4*)&h1[row];
        float4 o1 = *(const float4*)&h1[row + 4];
        float old_[8] = {o0.x, o0.y, o0.z, o0.w, o1.x, o1.y, o1.z, o1.w};
        float o[8];
#pragma unroll
        for (int j = 0; j < 8; ++j)
            o[j] = old_[j] + gelu_tanh(acc[i][j] + bres[c0 + j]);
        *(float4*)&h1[row]     = make_float4(o[0], o[1], o[2], o[3]);
        *(float4*)&h1[row + 4] = make_float4(o[4], o[5], o[6], o[7]);
    }
}

// ---------------------------------------------------------------------------
// K3: out = (h @ Wout + bout) * (rbf @ Wrbf); scalar = out . Wfin;
//     then atomic segment-sum (energy by batch[src], forces by src*vec_hat).
// BM=32 rows/block, FULL N=512 (needed for the Wfin reduction). 256 thr, 8x8.
// ---------------------------------------------------------------------------
__global__ __launch_bounds__(256) void k3_final(
    const float* __restrict__ h, const float* __restrict__ Wout,
    const float* __restrict__ bout, const float* __restrict__ Wrbf,
    const float* __restrict__ Wfin, const float* __restrict__ dist,
    const int* __restrict__ ei, const int* __restrict__ batch,
    const float* __restrict__ vec_hat,
    float* __restrict__ out_energy, float* __restrict__ out_forces,
    int isForce)
{
    __shared__ float As[16][36];
    __shared__ float Bs[16][EMBED];
    __shared__ float rbfL[32][52];
    __shared__ float red[32][65];   // stride 65 -> conflict-free column reduce

    const int tid = threadIdx.x;
    const int e0 = blockIdx.x * 32;       // E % 32 == 0, no row guards needed
    const int ty = tid >> 6, tx = tid & 63;
    const int r0 = ty * 8, c0 = tx * 8;

    // Gaussian smearing tile (32 x 50)
    const float step  = 12.0f / 49.0f;
    const float coeff = -0.5f / (step * step);
    for (int idx = tid; idx < 32 * NGAUSS; idx += 256) {
        int r = idx / NGAUSS, g = idx % NGAUSS;
        float t = dist[e0 + r] - (float)g * step;
        rbfL[r][g] = expf(coeff * t * t);
    }

    float acc[8][8];
#pragma unroll
    for (int i = 0; i < 8; ++i)
#pragma unroll
        for (int j = 0; j < 8; ++j) acc[i][j] = 0.0f;

    for (int k0 = 0; k0 < FF; k0 += 16) {
#pragma unroll
        for (int i = 0; i < 2; ++i) {
            int idx = i * 256 + tid;
            int r = idx >> 4, kk = idx & 15;
            As[kk][r] = h[(size_t)(e0 + r) * FF + k0 + kk];
        }
#pragma unroll
        for (int i = 0; i < 8; ++i) {
            int f4 = i * 256 + tid;           // 2048 float4 total
            int kr = f4 >> 7, c4 = f4 & 127;  // 128 float4 per row
            *(float4*)&Bs[kr][c4 * 4] =
                *(const float4*)&Wout[(size_t)(k0 + kr) * EMBED + c4 * 4];
        }
        __syncthreads();
#pragma unroll
        for (int kk = 0; kk < 16; ++kk) {
            float4 a0 = *(const float4*)&As[kk][r0];
            float4 a1 = *(const float4*)&As[kk][r0 + 4];
            float4 b0 = *(const float4*)&Bs[kk][c0];
            float4 b1 = *(const float4*)&Bs[kk][c0 + 4];
            float a[8] = {a0.x, a0.y, a0.z, a0.w, a1.x, a1.y, a1.z, a1.w};
            float b[8] = {b0.x, b0.y, b0.z, b0.w, b1.x, b1.y, b1.z, b1.w};
#pragma unroll
            for (int i = 0; i < 8; ++i)
#pragma unroll
                for (int j = 0; j < 8; ++j) acc[i][j] += a[i] * b[j];
        }
        __syncthreads();
    }

    // Epilogue: m[i][j] = (acc+bout)*Wfin (in place), then
    // val[i] = sum_g rbf[i][g] * (sum_j m[i][j]*Wrbf[g][j])
    float wf[8], bo[8];
#pragma unroll
    for (int j = 0; j < 8; ++j) { wf[j] = Wfin[c0 + j]; bo[j] = bout[c0 + j]; }
#pragma unroll
    for (int i = 0; i < 8; ++i)
#pragma unroll
        for (int j = 0; j < 8; ++j) acc[i][j] = (acc[i][j] + bo[j]) * wf[j];

    float val[8];
#pragma unroll
    for (int i = 0; i < 8; ++i) val[i] = 0.0f;
    for (int g = 0; g < NGAUSS; ++g) {
        float4 w0 = *(const float4*)&Wrbf[(size_t)g * EMBED + c0];
        float4 w1 = *(const float4*)&Wrbf[(size_t)g * EMBED + c0 + 4];
        float w[8] = {w0.x, w0.y, w0.z, w0.w, w1.x, w1.y, w1.z, w1.w};
#pragma unroll
        for (int i = 0; i < 8; ++i) {
            float t = 0.0f;
#pragma unroll
            for (int j = 0; j < 8; ++j) t += acc[i][j] * w[j];
            val[i] += rbfL[r0 + i][g] * t;   // wave-uniform LDS read: broadcast
        }
    }

#pragma unroll
    for (int i = 0; i < 8; ++i) red[r0 + i][tx] = val[i];
    __syncthreads();

    if (tid < 32) {
        float s = 0.0f;
        for (int c = 0; c < 64; ++c) s += red[tid][c];
        int e = e0 + tid;
        int sn = ei[e];  // src
        if (!isForce) {
            atomicAdd(&out_energy[batch[sn]], s);
        } else {
            atomicAdd(&out_forces[sn * 3 + 0], s * vec_hat[e * 3 + 0]);
            atomicAdd(&out_forces[sn * 3 + 1], s * vec_hat[e * 3 + 1]);
            atomicAdd(&out_forces[sn * 3 + 2], s * vec_hat[e * 3 + 2]);
        }
    }
}

// ---------------------------------------------------------------------------
extern "C" void kernel_launch(void* const* d_in, const int* in_sizes, int n_in,
                              void* d_out, int out_size, void* d_ws, size_t ws_size,
                              hipStream_t stream)
{
    (void)in_sizes; (void)n_in; (void)ws_size;

    const float* x       = (const float*)d_in[0];
    // d_in[1] = pos (unused by the math, only defines n = 10000)
    const float* dist    = (const float*)d_in[2];
    const float* vec_hat = (const float*)d_in[3];
    const int*   batch   = (const int*)d_in[4];
    const int*   ei      = (const int*)d_in[5];
    const float* e_Win   = (const float*)d_in[6];
    const float* e_bin   = (const float*)d_in[7];
    const float* e_Wres  = (const float*)d_in[8];
    const float* e_bres  = (const float*)d_in[9];
    const float* e_Wout  = (const float*)d_in[10];
    const float* e_bout  = (const float*)d_in[11];
    const float* e_Wrbf  = (const float*)d_in[12];
    const float* e_Wfin  = (const float*)d_in[13];
    const float* f_Win   = (const float*)d_in[14];
    const float* f_bin   = (const float*)d_in[15];
    const float* f_Wres  = (const float*)d_in[16];
    const float* f_bres  = (const float*)d_in[17];
    const float* f_Wout  = (const float*)d_in[18];
    const float* f_bout  = (const float*)d_in[19];
    const float* f_Wrbf  = (const float*)d_in[20];
    const float* f_Wfin  = (const float*)d_in[21];

    float* out = (float*)d_out;
    float* h1e = (float*)d_ws;                       // E x FF f32 (409.6 MB)
    float* h1f = h1e + (size_t)E_EDGES * FF;         // E x FF f32 (409.6 MB)

    // d_out is poisoned 0xAA before every launch; atomics need zeros.
    hipMemsetAsync(d_out, 0, sizeof(float) * (size_t)out_size, stream);

    dim3 g1((E_EDGES + 127) / 128, FF / 128);
    k1_gemm_gelu<<<g1, 256, 0, stream>>>(x, ei, e_Win, e_bin, h1e);
    k1_gemm_gelu<<<g1, 256, 0, stream>>>(x, ei, f_Win, f_bin, h1f);

    dim3 g2(E_EDGES / 32);
    k2_resmlp<<<g2, 512, 0, stream>>>(h1e, e_Wres, e_bres);
    k2_resmlp<<<g2, 512, 0, stream>>>(h1f, f_Wres, f_bres);

    dim3 g3(E_EDGES / 32);
    k3_final<<<g3, 256, 0, stream>>>(h1e, e_Wout, e_bout, e_Wrbf, e_Wfin,
                                     dist, ei, batch, vec_hat,
                                     out, out + NGRAPHS, 0);
    k3_final<<<g3, 256, 0, stream>>>(h1f, f_Wout, f_bout, f_Wrbf, f_Wfin,
                                     dist, ei, batch, vec_hat,
                                     out, out + NGRAPHS, 1);
}

// Round 6
// 6030.272 us; speedup vs baseline: 3.2615x; 3.2615x over previous
//
#include <hip/hip_runtime.h>
#include <cmath>

#define E_EDGES 100000
#define NNODES  10000
#define NGRAPHS 64
#define EMBED   512
#define FF      1024
#define NGAUSS  50

typedef _Float16 half8 __attribute__((ext_vector_type(8)));
typedef _Float16 half4_t __attribute__((ext_vector_type(4)));
typedef float float4v __attribute__((ext_vector_type(4)));

__device__ __forceinline__ void gload16(const void* g, void* l) {
    __builtin_amdgcn_global_load_lds(
        (const __attribute__((address_space(1))) void*)g,
        (__attribute__((address_space(3))) void*)l, 16, 0, 0);
}

__device__ __forceinline__ float gelu_f(float v) {
    // tanh-approx gelu: tanh(u) = 1 - 2/(e^{2u}+1)
    float u = 0.7978845608028654f * (v + 0.044715f * v * v * v);
    float e = __expf(2.0f * u);
    float t = 1.0f - 2.0f / (e + 1.0f);
    return 0.5f * v * (1.0f + t);
}

// ---------------------------------------------------------------------------
// Prep kernels: fp32 -> fp16 hi/lo splits
// ---------------------------------------------------------------------------
__global__ void conv_x(const float* __restrict__ x, _Float16* __restrict__ xhi,
                       _Float16* __restrict__ xlo, long n4) {
    long t = (long)blockIdx.x * 256 + threadIdx.x;
    if (t >= n4) return;
    long i = t * 4;
    float4 v = *(const float4*)&x[i];
    half4_t h, l;
    float vv[4] = {v.x, v.y, v.z, v.w};
#pragma unroll
    for (int j = 0; j < 4; ++j) {
        _Float16 hh = (_Float16)vv[j];
        h[j] = hh; l[j] = (_Float16)(vv[j] - (float)hh);
    }
    *(half4_t*)&xhi[i] = h;
    *(half4_t*)&xlo[i] = l;
}

// W[K][N] row-major -> prep[kc8][n][8] where element j holds W[kc8*8+j][n]
__global__ void conv_w(const float* __restrict__ W, _Float16* __restrict__ Whi,
                       _Float16* __restrict__ Wlo, int total, int shiftN, int maskN) {
    int idx = blockIdx.x * 256 + threadIdx.x;
    if (idx >= total) return;
    int kc8 = idx >> shiftN;
    int n = idx & maskN;
    int N = maskN + 1;
    half8 h, l;
#pragma unroll
    for (int j = 0; j < 8; ++j) {
        float v = W[(size_t)(kc8 * 8 + j) * N + n];
        _Float16 hh = (_Float16)v;
        h[j] = hh; l[j] = (_Float16)(v - (float)hh);
    }
    *(half8*)&Whi[(size_t)idx * 8] = h;
    *(half8*)&Wlo[(size_t)idx * 8] = l;
}

// Wrbf[50][512] -> padded K=64 prep [kc8(8)][n(512)][8]
__global__ void conv_wrbf(const float* __restrict__ W, _Float16* __restrict__ Whi,
                          _Float16* __restrict__ Wlo) {
    int idx = blockIdx.x * 256 + threadIdx.x;  // 4096 total
    if (idx >= 8 * 512) return;
    int kc8 = idx >> 9, n = idx & 511;
    half8 h, l;
#pragma unroll
    for (int j = 0; j < 8; ++j) {
        int g = kc8 * 8 + j;
        float v = (g < NGAUSS) ? W[(size_t)g * EMBED + n] : 0.0f;
        _Float16 hh = (_Float16)v;
        h[j] = hh; l[j] = (_Float16)(v - (float)hh);
    }
    *(half8*)&Whi[(size_t)idx * 8] = h;
    *(half8*)&Wlo[(size_t)idx * 8] = l;
}

// Gaussian smearing: rbf[e][g] (g padded to 64), row-major stride 64, hi/lo fp16
__global__ void conv_rbf(const float* __restrict__ dist, _Float16* __restrict__ rhi,
                         _Float16* __restrict__ rlo) {
    int idx = blockIdx.x * 256 + threadIdx.x;  // E*64
    if (idx >= E_EDGES * 64) return;
    int e = idx >> 6, g = idx & 63;
    const float step = 12.0f / 49.0f;
    const float coeff = -0.5f / (step * step);
    float v = 0.0f;
    if (g < NGAUSS) {
        float t = dist[e] - (float)g * step;
        v = __expf(coeff * t * t);
    }
    _Float16 hh = (_Float16)v;
    rhi[idx] = hh;
    rlo[idx] = (_Float16)(v - (float)hh);
}

// ---------------------------------------------------------------------------
// MFMA GEMM, 128x128 tile, 4 waves (2x2 of 64x64), K-step 32 (hi/lo 3-pass).
// MODE 1: A = gather [x[src]|x[dst]|x[edge]] (K=1536), epi: gelu -> h planes
// MODE 3: A = h planes (K=1024) + rbf-proj pre-pass (K=64), epi: reduce->partial
// NOTE: no in-place mode here — any kernel whose grid splits N must not
// write the buffer it reads as A (cross-block RAW race, R1 post-mortem).
// ---------------------------------------------------------------------------
template <int MODE>
__global__ __launch_bounds__(256, 2) void gemm_k(
    const _Float16* __restrict__ Ahi, const _Float16* __restrict__ Alo,
    const _Float16* __restrict__ Bhi, const _Float16* __restrict__ Blo,
    const int* __restrict__ ei, const float* __restrict__ bias,
    _Float16* __restrict__ outHi, _Float16* __restrict__ outLo,
    const _Float16* __restrict__ rbfHi, const _Float16* __restrict__ rbfLo,
    const _Float16* __restrict__ WrbHi, const _Float16* __restrict__ WrbLo,
    const float* __restrict__ Wfin, float* __restrict__ partial,
    int Ktiles, int N)
{
    __shared__ __align__(16) _Float16 sA[2][4][128][8];  // [hi/lo][kc][row][8]
    __shared__ __align__(16) _Float16 sB[2][4][128][8];  // [hi/lo][kc][col][8]
    __shared__ float red[128][2];

    const int tid = threadIdx.x;
    const int lane = tid & 63;
    const int wid = tid >> 6;
    const int fr = lane & 15;      // frag row/col index
    const int kq = lane >> 4;      // k-quarter
    const int wr = (wid >> 1) * 64;
    const int wc = (wid & 1) * 64;
    const int e0 = blockIdx.x * 128;
    const int n0 = blockIdx.y * 128;

    _Float16* sAb = &sA[0][0][0][0];
    _Float16* sBb = &sB[0][0][0][0];

    // staging decomposition (2 issues per wave per array)
    int cw[2], kcA[2], nB[2];
    const _Float16* aHiB[2]; const _Float16* aLoB[2];
    const _Float16* rHiB[2]; const _Float16* rLoB[2];
    int nsrc[2], ndst[2], nedg[2];
#pragma unroll
    for (int iss = 0; iss < 2; ++iss) {
        int cwv = (wid * 2 + iss) * 64;
        cw[iss] = cwv;
        int c = cwv + lane;
        int rowA = c & 127;
        kcA[iss] = c >> 7;
        nB[iss] = (cwv & 127) + lane;
        int er = e0 + rowA; if (er >= E_EDGES) er = E_EDGES - 1;
        if constexpr (MODE == 1) {
            nsrc[iss] = ei[er];
            ndst[iss] = ei[E_EDGES + er];
            nedg[iss] = NNODES + er;
        } else {
            aHiB[iss] = Ahi + (size_t)er * FF + kcA[iss] * 8;
            aLoB[iss] = Alo + (size_t)er * FF + kcA[iss] * 8;
        }
        if constexpr (MODE == 3) {
            rHiB[iss] = rbfHi + (size_t)er * 64 + kcA[iss] * 8;
            rLoB[iss] = rbfLo + (size_t)er * 64 + kcA[iss] * 8;
        }
    }

    float4v acc[4][4];
    float4v racc[4][4];
#pragma unroll
    for (int i = 0; i < 4; ++i)
#pragma unroll
        for (int j = 0; j < 4; ++j) {
            acc[i][j] = (float4v){0.f, 0.f, 0.f, 0.f};
            racc[i][j] = (float4v){0.f, 0.f, 0.f, 0.f};
        }

    // ---- MODE 3: rbf-projection pre-pass (2 K-tiles over padded K=64) ----
    if constexpr (MODE == 3) {
        for (int kt = 0; kt < 2; ++kt) {
            int k0 = kt * 32;
#pragma unroll
            for (int iss = 0; iss < 2; ++iss) {
                gload16(rHiB[iss] + k0, sAb + cw[iss] * 8);
                gload16(rLoB[iss] + k0, sAb + 4096 + cw[iss] * 8);
                size_t bo = ((size_t)(kt * 4 + (cw[iss] >> 7)) * N + n0 + nB[iss]) * 8;
                gload16(WrbHi + bo, sBb + cw[iss] * 8);
                gload16(WrbLo + bo, sBb + 4096 + cw[iss] * 8);
            }
            __syncthreads();
            half8 ah[4], al[4], bh[4], bl[4];
#pragma unroll
            for (int f = 0; f < 4; ++f) {
                int r = wr + f * 16 + fr;
                ah[f] = *(const half8*)&sA[0][kq][r][0];
                al[f] = *(const half8*)&sA[1][kq][r][0];
                int cc = wc + f * 16 + fr;
                bh[f] = *(const half8*)&sB[0][kq][cc][0];
                bl[f] = *(const half8*)&sB[1][kq][cc][0];
            }
#pragma unroll
            for (int fi = 0; fi < 4; ++fi)
#pragma unroll
                for (int fj = 0; fj < 4; ++fj) {
                    racc[fi][fj] = __builtin_amdgcn_mfma_f32_16x16x32_f16(ah[fi], bh[fj], racc[fi][fj], 0, 0, 0);
                    racc[fi][fj] = __builtin_amdgcn_mfma_f32_16x16x32_f16(ah[fi], bl[fj], racc[fi][fj], 0, 0, 0);
                    racc[fi][fj] = __builtin_amdgcn_mfma_f32_16x16x32_f16(al[fi], bh[fj], racc[fi][fj], 0, 0, 0);
                }
            __syncthreads();
        }
    }

    // ---- main K loop ----
    for (int kt = 0; kt < Ktiles; ++kt) {
        int k0 = kt * 32;
#pragma unroll
        for (int iss = 0; iss < 2; ++iss) {
            const _Float16 *srcH, *srcL;
            if constexpr (MODE == 1) {
                int sec = k0 >> 9;
                int node = (sec == 0) ? nsrc[iss] : (sec == 1) ? ndst[iss] : nedg[iss];
                size_t off = (size_t)node * EMBED + (k0 & 511) + kcA[iss] * 8;
                srcH = Ahi + off; srcL = Alo + off;
            } else {
                srcH = aHiB[iss] + k0; srcL = aLoB[iss] + k0;
            }
            gload16(srcH, sAb + cw[iss] * 8);
            gload16(srcL, sAb + 4096 + cw[iss] * 8);
            size_t bo = ((size_t)(kt * 4 + (cw[iss] >> 7)) * N + n0 + nB[iss]) * 8;
            gload16(Bhi + bo, sBb + cw[iss] * 8);
            gload16(Blo + bo, sBb + 4096 + cw[iss] * 8);
        }
        __syncthreads();
        half8 ah[4], al[4], bh[4], bl[4];
#pragma unroll
        for (int f = 0; f < 4; ++f) {
            int r = wr + f * 16 + fr;
            ah[f] = *(const half8*)&sA[0][kq][r][0];
            al[f] = *(const half8*)&sA[1][kq][r][0];
            int cc = wc + f * 16 + fr;
            bh[f] = *(const half8*)&sB[0][kq][cc][0];
            bl[f] = *(const half8*)&sB[1][kq][cc][0];
        }
#pragma unroll
        for (int fi = 0; fi < 4; ++fi)
#pragma unroll
            for (int fj = 0; fj < 4; ++fj) {
                acc[fi][fj] = __builtin_amdgcn_mfma_f32_16x16x32_f16(ah[fi], bh[fj], acc[fi][fj], 0, 0, 0);
                acc[fi][fj] = __builtin_amdgcn_mfma_f32_16x16x32_f16(ah[fi], bl[fj], acc[fi][fj], 0, 0, 0);
                acc[fi][fj] = __builtin_amdgcn_mfma_f32_16x16x32_f16(al[fi], bh[fj], acc[fi][fj], 0, 0, 0);
            }
        __syncthreads();
    }

    // ---- epilogues ----
    if constexpr (MODE == 1) {
#pragma unroll
        for (int fj = 0; fj < 4; ++fj) {
            int col = n0 + wc + fj * 16 + fr;
            float bo = bias[col];
#pragma unroll
            for (int fi = 0; fi < 4; ++fi) {
                int rowb = e0 + wr + fi * 16 + 4 * kq;
#pragma unroll
                for (int i = 0; i < 4; ++i) {
                    int row = rowb + i;
                    if (row < E_EDGES) {
                        float v = gelu_f(acc[fi][fj][i] + bo);
                        _Float16 h = (_Float16)v;
                        size_t o = (size_t)row * FF + col;
                        outHi[o] = h;
                        outLo[o] = (_Float16)(v - (float)h);
                    }
                }
            }
        }
    } else {
        float rs[4][4];
#pragma unroll
        for (int fi = 0; fi < 4; ++fi)
#pragma unroll
            for (int i = 0; i < 4; ++i) rs[fi][i] = 0.0f;
#pragma unroll
        for (int fj = 0; fj < 4; ++fj) {
            int col = n0 + wc + fj * 16 + fr;
            float wf = Wfin[col];
            float bo = bias[col];
#pragma unroll
            for (int fi = 0; fi < 4; ++fi)
#pragma unroll
                for (int i = 0; i < 4; ++i)
                    rs[fi][i] += (acc[fi][fj][i] + bo) * wf * racc[fi][fj][i];
        }
#pragma unroll
        for (int fi = 0; fi < 4; ++fi)
#pragma unroll
            for (int i = 0; i < 4; ++i) {
                float s = rs[fi][i];
                s += __shfl_xor(s, 1, 64);
                s += __shfl_xor(s, 2, 64);
                s += __shfl_xor(s, 4, 64);
                s += __shfl_xor(s, 8, 64);
                if (fr == 0) red[wr + fi * 16 + 4 * kq + i][wid & 1] = s;
            }
        __syncthreads();
        if (tid < 128) {
            int e = e0 + tid;
            if (e < E_EDGES) atomicAdd(&partial[e], red[tid][0] + red[tid][1]);
        }
    }
}

// ---------------------------------------------------------------------------
// k2_fullN: h <- h + gelu(h @ Wres + bres), in place, RACE-FREE:
// each block owns 64 rows completely (full N=1024). 512 threads = 8 waves
// arranged 2 (row-groups of 32) x 4 (col-groups of 256). K-step 32, hi/lo.
// LDS: A 8 KB + B 128 KB = 136 KB (1 block/CU).
// ---------------------------------------------------------------------------
__global__ __launch_bounds__(512, 2) void k2_fullN(
    const _Float16* __restrict__ Ahi, const _Float16* __restrict__ Alo,
    const _Float16* __restrict__ Bhi, const _Float16* __restrict__ Blo,
    const float* __restrict__ bias,
    _Float16* __restrict__ outHi, _Float16* __restrict__ outLo)
{
    __shared__ __align__(16) _Float16 sA[2][4][64][8];    // [hi/lo][kc][row][8]
    __shared__ __align__(16) _Float16 sB[2][4][1024][8];  // [hi/lo][kc][col][8]

    const int tid = threadIdx.x;
    const int lane = tid & 63;
    const int wid = tid >> 6;
    const int fr = lane & 15;
    const int kq = lane >> 4;
    const int wr = (wid >> 2) * 32;       // 0 or 32
    const int wc = (wid & 3) * 256;       // 0,256,512,768
    const int e0 = blockIdx.x * 64;

    _Float16* sAb = &sA[0][0][0][0];
    _Float16* sBb = &sB[0][0][0][0];

    // A staging: 8 chunks (2 planes x 4 kc), one per wave; lane = row.
    const int apl = wid >> 2;             // 0=hi, 1=lo
    const int akc = wid & 3;
    int arow = e0 + lane; if (arow >= E_EDGES) arow = E_EDGES - 1;
    const _Float16* aSrc = (apl ? Alo : Ahi) + (size_t)arow * FF + akc * 8;
    _Float16* aDst = sAb + apl * 2048 + akc * 512;  // + lane*8 by HW

    float4v acc[2][16];
#pragma unroll
    for (int i = 0; i < 2; ++i)
#pragma unroll
        for (int j = 0; j < 16; ++j) acc[i][j] = (float4v){0.f, 0.f, 0.f, 0.f};

    for (int kt = 0; kt < 32; ++kt) {
        int k0 = kt * 32;
        gload16(aSrc + k0, aDst);
        // B staging: 128 chunks of 512 elems; 16 per wave.
#pragma unroll
        for (int t = 0; t < 16; ++t) {
            int ci = wid * 16 + t;
            int pl = ci >> 6;             // 0..1
            int r  = ci & 63;
            int kc = r >> 4;              // 0..3
            int c0 = (r & 15) * 64;       // 0..960
            const _Float16* bsrc = (pl ? Blo : Bhi) +
                ((size_t)(kt * 4 + kc) * FF + c0 + lane) * 8;
            gload16(bsrc, sBb + pl * 32768 + (kc * 1024 + c0) * 8);
        }
        __syncthreads();

        half8 ah[2], al[2];
#pragma unroll
        for (int fi = 0; fi < 2; ++fi) {
            int r = wr + fi * 16 + fr;
            ah[fi] = *(const half8*)&sA[0][kq][r][0];
            al[fi] = *(const half8*)&sA[1][kq][r][0];
        }
#pragma unroll
        for (int fj = 0; fj < 16; ++fj) {
            int cc = wc + fj * 16 + fr;
            half8 bh = *(const half8*)&sB[0][kq][cc][0];
            half8 bl = *(const half8*)&sB[1][kq][cc][0];
#pragma unroll
            for (int fi = 0; fi < 2; ++fi) {
                acc[fi][fj] = __builtin_amdgcn_mfma_f32_16x16x32_f16(ah[fi], bh, acc[fi][fj], 0, 0, 0);
                acc[fi][fj] = __builtin_amdgcn_mfma_f32_16x16x32_f16(ah[fi], bl, acc[fi][fj], 0, 0, 0);
                acc[fi][fj] = __builtin_amdgcn_mfma_f32_16x16x32_f16(al[fi], bh, acc[fi][fj], 0, 0, 0);
            }
        }
        __syncthreads();
    }

    // Epilogue: h += gelu(acc + bias), in place (this block owns its rows).
#pragma unroll
    for (int fj = 0; fj < 16; ++fj) {
        int col = wc + fj * 16 + fr;
        float bo = bias[col];
#pragma unroll
        for (int fi = 0; fi < 2; ++fi) {
            int rowb = e0 + wr + fi * 16 + 4 * kq;
#pragma unroll
            for (int i = 0; i < 4; ++i) {
                int row = rowb + i;
                if (row < E_EDGES) {
                    size_t o = (size_t)row * FF + col;
                    float v = (float)Ahi[o] + (float)Alo[o] + gelu_f(acc[fi][fj][i] + bo);
                    _Float16 h = (_Float16)v;
                    outHi[o] = h;
                    outLo[o] = (_Float16)(v - (float)h);
                }
            }
        }
    }
}

// ---------------------------------------------------------------------------
// Finalize: energy = segsum(partial_e by batch[src]); forces = segsum(pf*vec by src)
// ---------------------------------------------------------------------------
__global__ void finalize(const float* __restrict__ pe, const float* __restrict__ pf,
                         const int* __restrict__ ei, const int* __restrict__ batch,
                         const float* __restrict__ vec_hat,
                         float* __restrict__ energy, float* __restrict__ forces) {
    __shared__ float bins[NGRAPHS];
    int t = blockIdx.x * 256 + threadIdx.x;
    if (threadIdx.x < NGRAPHS) bins[threadIdx.x] = 0.0f;
    __syncthreads();
    if (t < E_EDGES) {
        int s = ei[t];
        atomicAdd(&bins[batch[s]], pe[t]);
        float sf = pf[t];
        atomicAdd(&forces[s * 3 + 0], sf * vec_hat[t * 3 + 0]);
        atomicAdd(&forces[s * 3 + 1], sf * vec_hat[t * 3 + 1]);
        atomicAdd(&forces[s * 3 + 2], sf * vec_hat[t * 3 + 2]);
    }
    __syncthreads();
    if (threadIdx.x < NGRAPHS) atomicAdd(&energy[threadIdx.x], bins[threadIdx.x]);
}

// ---------------------------------------------------------------------------
extern "C" void kernel_launch(void* const* d_in, const int* in_sizes, int n_in,
                              void* d_out, int out_size, void* d_ws, size_t ws_size,
                              hipStream_t stream)
{
    (void)in_sizes; (void)n_in; (void)ws_size;

    const float* x       = (const float*)d_in[0];
    const float* dist    = (const float*)d_in[2];
    const float* vec_hat = (const float*)d_in[3];
    const int*   batch   = (const int*)d_in[4];
    const int*   ei      = (const int*)d_in[5];
    const float* e_Win   = (const float*)d_in[6];
    const float* e_bin   = (const float*)d_in[7];
    const float* e_Wres  = (const float*)d_in[8];
    const float* e_bres  = (const float*)d_in[9];
    const float* e_Wout  = (const float*)d_in[10];
    const float* e_bout  = (const float*)d_in[11];
    const float* e_Wrbf  = (const float*)d_in[12];
    const float* e_Wfin  = (const float*)d_in[13];
    const float* f_Win   = (const float*)d_in[14];
    const float* f_bin   = (const float*)d_in[15];
    const float* f_Wres  = (const float*)d_in[16];
    const float* f_bres  = (const float*)d_in[17];
    const float* f_Wout  = (const float*)d_in[18];
    const float* f_bout  = (const float*)d_in[19];
    const float* f_Wrbf  = (const float*)d_in[20];
    const float* f_Wfin  = (const float*)d_in[21];

    float* out = (float*)d_out;

    // ws layout
    char* w = (char*)d_ws;
    size_t off = 0;
    auto alloc = [&](size_t bytes) -> void* {
        void* p = w + off;
        off += (bytes + 255) & ~(size_t)255;
        return p;
    };
    const size_t NX = (size_t)(NNODES + E_EDGES) * EMBED;      // 56,320,000
    _Float16* xhi = (_Float16*)alloc(NX * 2);
    _Float16* xlo = (_Float16*)alloc(NX * 2);
    _Float16* hHi = (_Float16*)alloc((size_t)E_EDGES * FF * 2);
    _Float16* hLo = (_Float16*)alloc((size_t)E_EDGES * FF * 2);
    _Float16* rbfHi = (_Float16*)alloc((size_t)E_EDGES * 64 * 2);
    _Float16* rbfLo = (_Float16*)alloc((size_t)E_EDGES * 64 * 2);
    _Float16 *WinH[2], *WinL[2], *WresH[2], *WresL[2], *WoutH[2], *WoutL[2], *WrbH[2], *WrbL[2];
    for (int b = 0; b < 2; ++b) {
        WinH[b]  = (_Float16*)alloc((size_t)1536 * 1024 * 2);
        WinL[b]  = (_Float16*)alloc((size_t)1536 * 1024 * 2);
        WresH[b] = (_Float16*)alloc((size_t)1024 * 1024 * 2);
        WresL[b] = (_Float16*)alloc((size_t)1024 * 1024 * 2);
        WoutH[b] = (_Float16*)alloc((size_t)1024 * 512 * 2);
        WoutL[b] = (_Float16*)alloc((size_t)1024 * 512 * 2);
        WrbH[b]  = (_Float16*)alloc((size_t)64 * 512 * 2);
        WrbL[b]  = (_Float16*)alloc((size_t)64 * 512 * 2);
    }
    float* pe = (float*)alloc((size_t)E_EDGES * 4);
    float* pf = (float*)alloc((size_t)E_EDGES * 4);

    hipMemsetAsync(d_out, 0, sizeof(float) * (size_t)out_size, stream);
    hipMemsetAsync(pe, 0, (size_t)E_EDGES * 4, stream);
    hipMemsetAsync(pf, 0, (size_t)E_EDGES * 4, stream);

    // prep
    conv_x<<<55000, 256, 0, stream>>>(x, xhi, xlo, NX / 4);
    conv_rbf<<<25000, 256, 0, stream>>>(dist, rbfHi, rbfLo);
    conv_w<<<768, 256, 0, stream>>>(e_Win, WinH[0], WinL[0], 196608, 10, 1023);
    conv_w<<<768, 256, 0, stream>>>(f_Win, WinH[1], WinL[1], 196608, 10, 1023);
    conv_w<<<512, 256, 0, stream>>>(e_Wres, WresH[0], WresL[0], 131072, 10, 1023);
    conv_w<<<512, 256, 0, stream>>>(f_Wres, WresH[1], WresL[1], 131072, 10, 1023);
    conv_w<<<256, 256, 0, stream>>>(e_Wout, WoutH[0], WoutL[0], 65536, 9, 511);
    conv_w<<<256, 256, 0, stream>>>(f_Wout, WoutH[1], WoutL[1], 65536, 9, 511);
    conv_wrbf<<<16, 256, 0, stream>>>(e_Wrbf, WrbH[0], WrbL[0]);
    conv_wrbf<<<16, 256, 0, stream>>>(f_Wrbf, WrbH[1], WrbL[1]);

    const int MB = (E_EDGES + 127) / 128;  // 782
    const int MB64 = (E_EDGES + 63) / 64;  // 1563
    const float* bin_[2]  = {e_bin, f_bin};
    const float* bres_[2] = {e_bres, f_bres};
    const float* bout_[2] = {e_bout, f_bout};
    const float* wfin_[2] = {e_Wfin, f_Wfin};
    float* part_[2] = {pe, pf};

    for (int b = 0; b < 2; ++b) {
        gemm_k<1><<<dim3(MB, 8), 256, 0, stream>>>(
            xhi, xlo, WinH[b], WinL[b], ei, bin_[b], hHi, hLo,
            nullptr, nullptr, nullptr, nullptr, nullptr, nullptr, 48, FF);
        k2_fullN<<<dim3(MB64), 512, 0, stream>>>(
            hHi, hLo, WresH[b], WresL[b], bres_[b], hHi, hLo);
        gemm_k<3><<<dim3(MB, 4), 256, 0, stream>>>(
            hHi, hLo, WoutH[b], WoutL[b], nullptr, bout_[b], nullptr, nullptr,
            rbfHi, rbfLo, WrbH[b], WrbL[b], wfin_[b], part_[b], 32, EMBED);
    }

    finalize<<<(E_EDGES + 255) / 256, 256, 0, stream>>>(pe, pf, ei, batch, vec_hat, out, out + NGRAPHS);
}

// Round 8
// 5334.829 us; speedup vs baseline: 3.6867x; 1.1304x over previous
//
#include <hip/hip_runtime.h>
#include <cmath>

#define E_EDGES 100000
#define NNODES  10000
#define NGRAPHS 64
#define EMBED   512
#define FF      1024
#define NGAUSS  50

typedef _Float16 half8 __attribute__((ext_vector_type(8)));
typedef _Float16 half4_t __attribute__((ext_vector_type(4)));
typedef float float4v __attribute__((ext_vector_type(4)));

__device__ __forceinline__ void gload16(const void* g, void* l) {
    __builtin_amdgcn_global_load_lds(
        (const __attribute__((address_space(1))) void*)g,
        (__attribute__((address_space(3))) void*)l, 16, 0, 0);
}

__device__ __forceinline__ float gelu_f(float v) {
    // tanh-approx gelu: tanh(u) = 1 - 2/(e^{2u}+1)
    float u = 0.7978845608028654f * (v + 0.044715f * v * v * v);
    float e = __expf(2.0f * u);
    float t = 1.0f - 2.0f / (e + 1.0f);
    return 0.5f * v * (1.0f + t);
}

// ---------------------------------------------------------------------------
// Prep kernels: fp32 -> fp16 hi/lo splits
// ---------------------------------------------------------------------------
__global__ void conv_x(const float* __restrict__ x, _Float16* __restrict__ xhi,
                       _Float16* __restrict__ xlo, long n4) {
    long t = (long)blockIdx.x * 256 + threadIdx.x;
    if (t >= n4) return;
    long i = t * 4;
    float4 v = *(const float4*)&x[i];
    half4_t h, l;
    float vv[4] = {v.x, v.y, v.z, v.w};
#pragma unroll
    for (int j = 0; j < 4; ++j) {
        _Float16 hh = (_Float16)vv[j];
        h[j] = hh; l[j] = (_Float16)(vv[j] - (float)hh);
    }
    *(half4_t*)&xhi[i] = h;
    *(half4_t*)&xlo[i] = l;
}

// W[K][N] row-major -> prep[kc8][n][8] where element j holds W[kc8*8+j][n]
__global__ void conv_w(const float* __restrict__ W, _Float16* __restrict__ Whi,
                       _Float16* __restrict__ Wlo, int total, int shiftN, int maskN) {
    int idx = blockIdx.x * 256 + threadIdx.x;
    if (idx >= total) return;
    int kc8 = idx >> shiftN;
    int n = idx & maskN;
    int N = maskN + 1;
    half8 h, l;
#pragma unroll
    for (int j = 0; j < 8; ++j) {
        float v = W[(size_t)(kc8 * 8 + j) * N + n];
        _Float16 hh = (_Float16)v;
        h[j] = hh; l[j] = (_Float16)(v - (float)hh);
    }
    *(half8*)&Whi[(size_t)idx * 8] = h;
    *(half8*)&Wlo[(size_t)idx * 8] = l;
}

// Wrbf[50][512] -> padded K=64 prep [kc8(8)][n(512)][8]
__global__ void conv_wrbf(const float* __restrict__ W, _Float16* __restrict__ Whi,
                          _Float16* __restrict__ Wlo) {
    int idx = blockIdx.x * 256 + threadIdx.x;  // 4096 total
    if (idx >= 8 * 512) return;
    int kc8 = idx >> 9, n = idx & 511;
    half8 h, l;
#pragma unroll
    for (int j = 0; j < 8; ++j) {
        int g = kc8 * 8 + j;
        float v = (g < NGAUSS) ? W[(size_t)g * EMBED + n] : 0.0f;
        _Float16 hh = (_Float16)v;
        h[j] = hh; l[j] = (_Float16)(v - (float)hh);
    }
    *(half8*)&Whi[(size_t)idx * 8] = h;
    *(half8*)&Wlo[(size_t)idx * 8] = l;
}

// Gaussian smearing: rbf[e][g] (g padded to 64), row-major stride 64, hi/lo fp16
__global__ void conv_rbf(const float* __restrict__ dist, _Float16* __restrict__ rhi,
                         _Float16* __restrict__ rlo) {
    int idx = blockIdx.x * 256 + threadIdx.x;  // E*64
    if (idx >= E_EDGES * 64) return;
    int e = idx >> 6, g = idx & 63;
    const float step = 12.0f / 49.0f;
    const float coeff = -0.5f / (step * step);
    float v = 0.0f;
    if (g < NGAUSS) {
        float t = dist[e] - (float)g * step;
        v = __expf(coeff * t * t);
    }
    _Float16 hh = (_Float16)v;
    rhi[idx] = hh;
    rlo[idx] = (_Float16)(v - (float)hh);
}

// ---------------------------------------------------------------------------
// MFMA GEMM, 128x128 tile, 4 waves (2x2 of 64x64), K-step 32 (hi/lo 3-pass).
// MODE 1: A = gather [x[src]|x[dst]|x[edge]] (K=1536), epi: gelu -> h planes
// MODE 3: A = h planes (K=1024) + rbf-proj pre-pass (K=64), epi: reduce->partial
// A-staging lane remap (R6): lane = piece*16 + rowg; the 4 lanes sharing a row
// read one aligned 64B line (no granule waste). LDS A = [pl][grp8][piece4][16][8].
// Grid transposed: blockIdx.x = n-block (fast) so A-panel sharers are adjacent.
// NOTE: no in-place mode — grid splits N (cross-block RAW race, R1).
// ---------------------------------------------------------------------------
template <int MODE>
__global__ __launch_bounds__(256, 2) void gemm_k(
    const _Float16* __restrict__ Ahi, const _Float16* __restrict__ Alo,
    const _Float16* __restrict__ Bhi, const _Float16* __restrict__ Blo,
    const int* __restrict__ ei, const float* __restrict__ bias,
    _Float16* __restrict__ outHi, _Float16* __restrict__ outLo,
    const _Float16* __restrict__ rbfHi, const _Float16* __restrict__ rbfLo,
    const _Float16* __restrict__ WrbHi, const _Float16* __restrict__ WrbLo,
    const float* __restrict__ Wfin, float* __restrict__ partial,
    int Ktiles, int N)
{
    __shared__ __align__(16) _Float16 sA[2][8][4][16][8];  // [pl][grp][piece][row16][8]
    __shared__ __align__(16) _Float16 sB[2][4][128][8];    // [pl][kc][col][8]
    __shared__ float red[128][2];

    const int tid = threadIdx.x;
    const int lane = tid & 63;
    const int wid = tid >> 6;
    const int fr = lane & 15;      // frag row/col index
    const int kq = lane >> 4;      // k-quarter
    const int wr = (wid >> 1) * 64;
    const int wc = (wid & 1) * 64;
    const int e0 = blockIdx.y * 128;   // transposed grid
    const int n0 = blockIdx.x * 128;

    _Float16* sAb = &sA[0][0][0][0][0];
    _Float16* sBb = &sB[0][0][0][0];

    // ---- A staging setup: 16 issues (2 planes x 8 row-groups), 4 per wave ----
    const int rowg = lane & 15;
    const int piece = lane >> 4;
    int aplA[4], agrpA[4];
    int nsrcA[4], ndstA[4], nedgA[4];
    const _Float16* aPtr[4];
    const _Float16* rPtr[4];
#pragma unroll
    for (int i = 0; i < 4; ++i) {
        int idx = wid * 4 + i;
        int apl = idx >> 3, agrp = idx & 7;
        aplA[i] = apl; agrpA[i] = agrp;
        int er = e0 + agrp * 16 + rowg;
        if (er >= E_EDGES) er = E_EDGES - 1;
        if constexpr (MODE == 1) {
            nsrcA[i] = ei[er];
            ndstA[i] = ei[E_EDGES + er];
            nedgA[i] = NNODES + er;
        } else {
            aPtr[i] = (apl ? Alo : Ahi) + (size_t)er * FF + piece * 8;
        }
        if constexpr (MODE == 3) {
            rPtr[i] = (apl ? rbfLo : rbfHi) + (size_t)er * 64 + piece * 8;
        }
    }

    // ---- B staging setup: 2 issues per wave per plane ----
    int cwB[2], nB[2];
#pragma unroll
    for (int iss = 0; iss < 2; ++iss) {
        int cwv = (wid * 2 + iss) * 64;
        cwB[iss] = cwv;
        nB[iss] = (cwv & 127) + lane;
    }

    float4v acc[4][4];
    float4v racc[4][4];
#pragma unroll
    for (int i = 0; i < 4; ++i)
#pragma unroll
        for (int j = 0; j < 4; ++j) {
            acc[i][j] = (float4v){0.f, 0.f, 0.f, 0.f};
            racc[i][j] = (float4v){0.f, 0.f, 0.f, 0.f};
        }

    // ---- MODE 3: rbf-projection pre-pass (2 K-tiles over padded K=64) ----
    if constexpr (MODE == 3) {
        for (int kt = 0; kt < 2; ++kt) {
            int k0 = kt * 32;
#pragma unroll
            for (int i = 0; i < 4; ++i)
                gload16(rPtr[i] + k0, sAb + (size_t)(aplA[i] * 8 + agrpA[i]) * 512);
#pragma unroll
            for (int iss = 0; iss < 2; ++iss) {
                size_t bo = ((size_t)(kt * 4 + (cwB[iss] >> 7)) * N + n0 + nB[iss]) * 8;
                gload16(WrbHi + bo, sBb + cwB[iss] * 8);
                gload16(WrbLo + bo, sBb + 4096 + cwB[iss] * 8);
            }
            __syncthreads();
            half8 ah[4], al[4], bh[4], bl[4];
#pragma unroll
            for (int f = 0; f < 4; ++f) {
                ah[f] = *(const half8*)&sA[0][(wr >> 4) + f][kq][fr][0];
                al[f] = *(const half8*)&sA[1][(wr >> 4) + f][kq][fr][0];
                int cc = wc + f * 16 + fr;
                bh[f] = *(const half8*)&sB[0][kq][cc][0];
                bl[f] = *(const half8*)&sB[1][kq][cc][0];
            }
#pragma unroll
            for (int fi = 0; fi < 4; ++fi)
#pragma unroll
                for (int fj = 0; fj < 4; ++fj) {
                    racc[fi][fj] = __builtin_amdgcn_mfma_f32_16x16x32_f16(ah[fi], bh[fj], racc[fi][fj], 0, 0, 0);
                    racc[fi][fj] = __builtin_amdgcn_mfma_f32_16x16x32_f16(ah[fi], bl[fj], racc[fi][fj], 0, 0, 0);
                    racc[fi][fj] = __builtin_amdgcn_mfma_f32_16x16x32_f16(al[fi], bh[fj], racc[fi][fj], 0, 0, 0);
                }
            __syncthreads();
        }
    }

    // ---- main K loop ----
    for (int kt = 0; kt < Ktiles; ++kt) {
        int k0 = kt * 32;
        if constexpr (MODE == 1) {
            int sec = k0 >> 9;                       // wave-uniform section
            int ks = (k0 & 511) + piece * 8;
#pragma unroll
            for (int i = 0; i < 4; ++i) {
                int node = (sec == 0) ? nsrcA[i] : (sec == 1) ? ndstA[i] : nedgA[i];
                const _Float16* s = (aplA[i] ? Alo : Ahi) + (size_t)node * EMBED + ks;
                gload16(s, sAb + (size_t)(aplA[i] * 8 + agrpA[i]) * 512);
            }
        } else {
#pragma unroll
            for (int i = 0; i < 4; ++i)
                gload16(aPtr[i] + k0, sAb + (size_t)(aplA[i] * 8 + agrpA[i]) * 512);
        }
#pragma unroll
        for (int iss = 0; iss < 2; ++iss) {
            size_t bo = ((size_t)(kt * 4 + (cwB[iss] >> 7)) * N + n0 + nB[iss]) * 8;
            gload16(Bhi + bo, sBb + cwB[iss] * 8);
            gload16(Blo + bo, sBb + 4096 + cwB[iss] * 8);
        }
        __syncthreads();
        half8 ah[4], al[4], bh[4], bl[4];
#pragma unroll
        for (int f = 0; f < 4; ++f) {
            ah[f] = *(const half8*)&sA[0][(wr >> 4) + f][kq][fr][0];
            al[f] = *(const half8*)&sA[1][(wr >> 4) + f][kq][fr][0];
            int cc = wc + f * 16 + fr;
            bh[f] = *(const half8*)&sB[0][kq][cc][0];
            bl[f] = *(const half8*)&sB[1][kq][cc][0];
        }
#pragma unroll
        for (int fi = 0; fi < 4; ++fi)
#pragma unroll
            for (int fj = 0; fj < 4; ++fj) {
                acc[fi][fj] = __builtin_amdgcn_mfma_f32_16x16x32_f16(ah[fi], bh[fj], acc[fi][fj], 0, 0, 0);
                acc[fi][fj] = __builtin_amdgcn_mfma_f32_16x16x32_f16(ah[fi], bl[fj], acc[fi][fj], 0, 0, 0);
                acc[fi][fj] = __builtin_amdgcn_mfma_f32_16x16x32_f16(al[fi], bh[fj], acc[fi][fj], 0, 0, 0);
            }
        __syncthreads();
    }

    // ---- epilogues ----
    if constexpr (MODE == 1) {
#pragma unroll
        for (int fj = 0; fj < 4; ++fj) {
            int col = n0 + wc + fj * 16 + fr;
            float bo = bias[col];
#pragma unroll
            for (int fi = 0; fi < 4; ++fi) {
                int rowb = e0 + wr + fi * 16 + 4 * kq;
#pragma unroll
                for (int i = 0; i < 4; ++i) {
                    int row = rowb + i;
                    if (row < E_EDGES) {
                        float v = gelu_f(acc[fi][fj][i] + bo);
                        _Float16 h = (_Float16)v;
                        size_t o = (size_t)row * FF + col;
                        outHi[o] = h;
                        outLo[o] = (_Float16)(v - (float)h);
                    }
                }
            }
        }
    } else {
        float rs[4][4];
#pragma unroll
        for (int fi = 0; fi < 4; ++fi)
#pragma unroll
            for (int i = 0; i < 4; ++i) rs[fi][i] = 0.0f;
#pragma unroll
        for (int fj = 0; fj < 4; ++fj) {
            int col = n0 + wc + fj * 16 + fr;
            float wf = Wfin[col];
            float bo = bias[col];
#pragma unroll
            for (int fi = 0; fi < 4; ++fi)
#pragma unroll
                for (int i = 0; i < 4; ++i)
                    rs[fi][i] += (acc[fi][fj][i] + bo) * wf * racc[fi][fj][i];
        }
#pragma unroll
        for (int fi = 0; fi < 4; ++fi)
#pragma unroll
            for (int i = 0; i < 4; ++i) {
                float s = rs[fi][i];
                s += __shfl_xor(s, 1, 64);
                s += __shfl_xor(s, 2, 64);
                s += __shfl_xor(s, 4, 64);
                s += __shfl_xor(s, 8, 64);
                if (fr == 0) red[wr + fi * 16 + 4 * kq + i][wid & 1] = s;
            }
        __syncthreads();
        if (tid < 128) {
            int e = e0 + tid;
            if (e < E_EDGES) atomicAdd(&partial[e], red[tid][0] + red[tid][1]);
        }
    }
}

// ---------------------------------------------------------------------------
// k2_fullN: h <- h + gelu(h @ Wres + bres), in place, RACE-FREE (block owns
// its 64 rows completely, full N=1024). 512 threads = 8 waves (2x4).
// A staging uses the same 64B-line lane remap: LDS A = [pl][grp4][piece4][16][8].
// ---------------------------------------------------------------------------
__global__ __launch_bounds__(512, 2) void k2_fullN(
    const _Float16* __restrict__ Ahi, const _Float16* __restrict__ Alo,
    const _Float16* __restrict__ Bhi, const _Float16* __restrict__ Blo,
    const float* __restrict__ bias,
    _Float16* __restrict__ outHi, _Float16* __restrict__ outLo)
{
    __shared__ __align__(16) _Float16 sA[2][4][4][16][8];  // [pl][grp][piece][row16][8]
    __shared__ __align__(16) _Float16 sB[2][4][1024][8];   // [pl][kc][col][8]

    const int tid = threadIdx.x;
    const int lane = tid & 63;
    const int wid = tid >> 6;
    const int fr = lane & 15;
    const int kq = lane >> 4;
    const int wr = (wid >> 2) * 32;       // 0 or 32
    const int wc = (wid & 3) * 256;       // 0,256,512,768
    const int e0 = blockIdx.x * 64;

    _Float16* sAb = &sA[0][0][0][0][0];
    _Float16* sBb = &sB[0][0][0][0];

    // A staging: 8 issues (2 planes x 4 row-groups), one per wave; remapped lanes.
    const int rowg = lane & 15;
    const int piece = lane >> 4;
    const int apl = wid >> 2;             // 0=hi, 1=lo
    const int agrp = wid & 3;
    int arow = e0 + agrp * 16 + rowg; if (arow >= E_EDGES) arow = E_EDGES - 1;
    const _Float16* aSrc = (apl ? Alo : Ahi) + (size_t)arow * FF + piece * 8;
    _Float16* aDst = sAb + (size_t)(apl * 4 + agrp) * 512;  // + lane*8 by HW

    float4v acc[2][16];
#pragma unroll
    for (int i = 0; i < 2; ++i)
#pragma unroll
        for (int j = 0; j < 16; ++j) acc[i][j] = (float4v){0.f, 0.f, 0.f, 0.f};

    for (int kt = 0; kt < 32; ++kt) {
        int k0 = kt * 32;
        gload16(aSrc + k0, aDst);
        // B staging: 128 chunks of 512 elems; 16 per wave (coalesced 1KB each).
#pragma unroll
        for (int t = 0; t < 16; ++t) {
            int ci = wid * 16 + t;
            int pl = ci >> 6;             // 0..1
            int r  = ci & 63;
            int kc = r >> 4;              // 0..3
            int c0 = (r & 15) * 64;       // 0..960
            const _Float16* bsrc = (pl ? Blo : Bhi) +
                ((size_t)(kt * 4 + kc) * FF + c0 + lane) * 8;
            gload16(bsrc, sBb + pl * 32768 + (kc * 1024 + c0) * 8);
        }
        __syncthreads();

        half8 ah[2], al[2];
#pragma unroll
        for (int fi = 0; fi < 2; ++fi) {
            ah[fi] = *(const half8*)&sA[0][(wr >> 4) + fi][kq][fr][0];
            al[fi] = *(const half8*)&sA[1][(wr >> 4) + fi][kq][fr][0];
        }
#pragma unroll
        for (int fj = 0; fj < 16; ++fj) {
            int cc = wc + fj * 16 + fr;
            half8 bh = *(const half8*)&sB[0][kq][cc][0];
            half8 bl = *(const half8*)&sB[1][kq][cc][0];
#pragma unroll
            for (int fi = 0; fi < 2; ++fi) {
                acc[fi][fj] = __builtin_amdgcn_mfma_f32_16x16x32_f16(ah[fi], bh, acc[fi][fj], 0, 0, 0);
                acc[fi][fj] = __builtin_amdgcn_mfma_f32_16x16x32_f16(ah[fi], bl, acc[fi][fj], 0, 0, 0);
                acc[fi][fj] = __builtin_amdgcn_mfma_f32_16x16x32_f16(al[fi], bh, acc[fi][fj], 0, 0, 0);
            }
        }
        __syncthreads();
    }

    // Epilogue: h += gelu(acc + bias), in place (this block owns its rows).
#pragma unroll
    for (int fj = 0; fj < 16; ++fj) {
        int col = wc + fj * 16 + fr;
        float bo = bias[col];
#pragma unroll
        for (int fi = 0; fi < 2; ++fi) {
            int rowb = e0 + wr + fi * 16 + 4 * kq;
#pragma unroll
            for (int i = 0; i < 4; ++i) {
                int row = rowb + i;
                if (row < E_EDGES) {
                    size_t o = (size_t)row * FF + col;
                    float v = (float)Ahi[o] + (float)Alo[o] + gelu_f(acc[fi][fj][i] + bo);
                    _Float16 h = (_Float16)v;
                    outHi[o] = h;
                    outLo[o] = (_Float16)(v - (float)h);
                }
            }
        }
    }
}

// ---------------------------------------------------------------------------
// Finalize: energy = segsum(partial_e by batch[src]); forces = segsum(pf*vec by src)
// ---------------------------------------------------------------------------
__global__ void finalize(const float* __restrict__ pe, const float* __restrict__ pf,
                         const int* __restrict__ ei, const int* __restrict__ batch,
                         const float* __restrict__ vec_hat,
                         float* __restrict__ energy, float* __restrict__ forces) {
    __shared__ float bins[NGRAPHS];
    int t = blockIdx.x * 256 + threadIdx.x;
    if (threadIdx.x < NGRAPHS) bins[threadIdx.x] = 0.0f;
    __syncthreads();
    if (t < E_EDGES) {
        int s = ei[t];
        atomicAdd(&bins[batch[s]], pe[t]);
        float sf = pf[t];
        atomicAdd(&forces[s * 3 + 0], sf * vec_hat[t * 3 + 0]);
        atomicAdd(&forces[s * 3 + 1], sf * vec_hat[t * 3 + 1]);
        atomicAdd(&forces[s * 3 + 2], sf * vec_hat[t * 3 + 2]);
    }
    __syncthreads();
    if (threadIdx.x < NGRAPHS) atomicAdd(&energy[threadIdx.x], bins[threadIdx.x]);
}

// ---------------------------------------------------------------------------
extern "C" void kernel_launch(void* const* d_in, const int* in_sizes, int n_in,
                              void* d_out, int out_size, void* d_ws, size_t ws_size,
                              hipStream_t stream)
{
    (void)in_sizes; (void)n_in; (void)ws_size;

    const float* x       = (const float*)d_in[0];
    const float* dist    = (const float*)d_in[2];
    const float* vec_hat = (const float*)d_in[3];
    const int*   batch   = (const int*)d_in[4];
    const int*   ei      = (const int*)d_in[5];
    const float* e_Win   = (const float*)d_in[6];
    const float* e_bin   = (const float*)d_in[7];
    const float* e_Wres  = (const float*)d_in[8];
    const float* e_bres  = (const float*)d_in[9];
    const float* e_Wout  = (const float*)d_in[10];
    const float* e_bout  = (const float*)d_in[11];
    const float* e_Wrbf  = (const float*)d_in[12];
    const float* e_Wfin  = (const float*)d_in[13];
    const float* f_Win   = (const float*)d_in[14];
    const float* f_bin   = (const float*)d_in[15];
    const float* f_Wres  = (const float*)d_in[16];
    const float* f_bres  = (const float*)d_in[17];
    const float* f_Wout  = (const float*)d_in[18];
    const float* f_bout  = (const float*)d_in[19];
    const float* f_Wrbf  = (const float*)d_in[20];
    const float* f_Wfin  = (const float*)d_in[21];

    float* out = (float*)d_out;

    // ws layout
    char* w = (char*)d_ws;
    size_t off = 0;
    auto alloc = [&](size_t bytes) -> void* {
        void* p = w + off;
        off += (bytes + 255) & ~(size_t)255;
        return p;
    };
    const size_t NX = (size_t)(NNODES + E_EDGES) * EMBED;      // 56,320,000
    _Float16* xhi = (_Float16*)alloc(NX * 2);
    _Float16* xlo = (_Float16*)alloc(NX * 2);
    _Float16* hHi = (_Float16*)alloc((size_t)E_EDGES * FF * 2);
    _Float16* hLo = (_Float16*)alloc((size_t)E_EDGES * FF * 2);
    _Float16* rbfHi = (_Float16*)alloc((size_t)E_EDGES * 64 * 2);
    _Float16* rbfLo = (_Float16*)alloc((size_t)E_EDGES * 64 * 2);
    _Float16 *WinH[2], *WinL[2], *WresH[2], *WresL[2], *WoutH[2], *WoutL[2], *WrbH[2], *WrbL[2];
    for (int b = 0; b < 2; ++b) {
        WinH[b]  = (_Float16*)alloc((size_t)1536 * 1024 * 2);
        WinL[b]  = (_Float16*)alloc((size_t)1536 * 1024 * 2);
        WresH[b] = (_Float16*)alloc((size_t)1024 * 1024 * 2);
        WresL[b] = (_Float16*)alloc((size_t)1024 * 1024 * 2);
        WoutH[b] = (_Float16*)alloc((size_t)1024 * 512 * 2);
        WoutL[b] = (_Float16*)alloc((size_t)1024 * 512 * 2);
        WrbH[b]  = (_Float16*)alloc((size_t)64 * 512 * 2);
        WrbL[b]  = (_Float16*)alloc((size_t)64 * 512 * 2);
    }
    float* pe = (float*)alloc((size_t)E_EDGES * 4);
    float* pf = (float*)alloc((size_t)E_EDGES * 4);

    hipMemsetAsync(d_out, 0, sizeof(float) * (size_t)out_size, stream);
    hipMemsetAsync(pe, 0, (size_t)E_EDGES * 4, stream);
    hipMemsetAsync(pf, 0, (size_t)E_EDGES * 4, stream);

    // prep
    conv_x<<<55000, 256, 0, stream>>>(x, xhi, xlo, NX / 4);
    conv_rbf<<<25000, 256, 0, stream>>>(dist, rbfHi, rbfLo);
    conv_w<<<768, 256, 0, stream>>>(e_Win, WinH[0], WinL[0], 196608, 10, 1023);
    conv_w<<<768, 256, 0, stream>>>(f_Win, WinH[1], WinL[1], 196608, 10, 1023);
    conv_w<<<512, 256, 0, stream>>>(e_Wres, WresH[0], WresL[0], 131072, 10, 1023);
    conv_w<<<512, 256, 0, stream>>>(f_Wres, WresH[1], WresL[1], 131072, 10, 1023);
    conv_w<<<256, 256, 0, stream>>>(e_Wout, WoutH[0], WoutL[0], 65536, 9, 511);
    conv_w<<<256, 256, 0, stream>>>(f_Wout, WoutH[1], WoutL[1], 65536, 9, 511);
    conv_wrbf<<<16, 256, 0, stream>>>(e_Wrbf, WrbH[0], WrbL[0]);
    conv_wrbf<<<16, 256, 0, stream>>>(f_Wrbf, WrbH[1], WrbL[1]);

    const int MB = (E_EDGES + 127) / 128;  // 782
    const int MB64 = (E_EDGES + 63) / 64;  // 1563
    const float* bin_[2]  = {e_bin, f_bin};
    const float* bres_[2] = {e_bres, f_bres};
    const float* bout_[2] = {e_bout, f_bout};
    const float* wfin_[2] = {e_Wfin, f_Wfin};
    float* part_[2] = {pe, pf};

    for (int b = 0; b < 2; ++b) {
        gemm_k<1><<<dim3(8, MB), 256, 0, stream>>>(
            xhi, xlo, WinH[b], WinL[b], ei, bin_[b], hHi, hLo,
            nullptr, nullptr, nullptr, nullptr, nullptr, nullptr, 48, FF);
        k2_fullN<<<dim3(MB64), 512, 0, stream>>>(
            hHi, hLo, WresH[b], WresL[b], bres_[b], hHi, hLo);
        gemm_k<3><<<dim3(4, MB), 256, 0, stream>>>(
            hHi, hLo, WoutH[b], WoutL[b], nullptr, bout_[b], nullptr, nullptr,
            rbfHi, rbfLo, WrbH[b], WrbL[b], wfin_[b], part_[b], 32, EMBED);
    }

    finalize<<<(E_EDGES + 255) / 256, 256, 0, stream>>>(pe, pf, ei, batch, vec_hat, out, out + NGRAPHS);
}

// Round 9
// 4202.035 us; speedup vs baseline: 4.6806x; 1.2696x over previous
//
#include <hip/hip_runtime.h>
#include <cmath>

#define E_EDGES 100000
#define NNODES  10000
#define NGRAPHS 64
#define EMBED   512
#define FF      1024
#define NGAUSS  50

typedef _Float16 half8 __attribute__((ext_vector_type(8)));
typedef _Float16 half4_t __attribute__((ext_vector_type(4)));
typedef float float4v __attribute__((ext_vector_type(4)));

__device__ __forceinline__ void gload16(const void* g, void* l) {
    __builtin_amdgcn_global_load_lds(
        (const __attribute__((address_space(1))) void*)g,
        (__attribute__((address_space(3))) void*)l, 16, 0, 0);
}

__device__ __forceinline__ float gelu_f(float v) {
    // tanh-approx gelu: tanh(u) = 1 - 2/(e^{2u}+1)
    float u = 0.7978845608028654f * (v + 0.044715f * v * v * v);
    float e = __expf(2.0f * u);
    float t = 1.0f - 2.0f / (e + 1.0f);
    return 0.5f * v * (1.0f + t);
}

// ---------------------------------------------------------------------------
// Prep kernels
// ---------------------------------------------------------------------------
__global__ void conv_x(const float* __restrict__ x, _Float16* __restrict__ xhi,
                       _Float16* __restrict__ xlo, long n4) {
    long t = (long)blockIdx.x * 256 + threadIdx.x;
    if (t >= n4) return;
    long i = t * 4;
    float4 v = *(const float4*)&x[i];
    half4_t h, l;
    float vv[4] = {v.x, v.y, v.z, v.w};
#pragma unroll
    for (int j = 0; j < 4; ++j) {
        _Float16 hh = (_Float16)vv[j];
        h[j] = hh; l[j] = (_Float16)(vv[j] - (float)hh);
    }
    *(half4_t*)&xhi[i] = h;
    *(half4_t*)&xlo[i] = l;
}

// W[K][N] row-major -> prep[kc8][n][8] where element j holds W[kc8*8+j][n]
__global__ void conv_w(const float* __restrict__ W, _Float16* __restrict__ Whi,
                       _Float16* __restrict__ Wlo, int total, int shiftN, int maskN) {
    int idx = blockIdx.x * 256 + threadIdx.x;
    if (idx >= total) return;
    int kc8 = idx >> shiftN;
    int n = idx & maskN;
    int N = maskN + 1;
    half8 h, l;
#pragma unroll
    for (int j = 0; j < 8; ++j) {
        float v = W[(size_t)(kc8 * 8 + j) * N + n];
        _Float16 hh = (_Float16)v;
        h[j] = hh; l[j] = (_Float16)(v - (float)hh);
    }
    *(half8*)&Whi[(size_t)idx * 8] = h;
    *(half8*)&Wlo[(size_t)idx * 8] = l;
}

// Wrbf[50][512] -> padded K=64 prep [kc8(8)][n(512)][8]
__global__ void conv_wrbf(const float* __restrict__ W, _Float16* __restrict__ Whi,
                          _Float16* __restrict__ Wlo) {
    int idx = blockIdx.x * 256 + threadIdx.x;  // 4096 total
    if (idx >= 8 * 512) return;
    int kc8 = idx >> 9, n = idx & 511;
    half8 h, l;
#pragma unroll
    for (int j = 0; j < 8; ++j) {
        int g = kc8 * 8 + j;
        float v = (g < NGAUSS) ? W[(size_t)g * EMBED + n] : 0.0f;
        _Float16 hh = (_Float16)v;
        h[j] = hh; l[j] = (_Float16)(v - (float)hh);
    }
    *(half8*)&Whi[(size_t)idx * 8] = h;
    *(half8*)&Wlo[(size_t)idx * 8] = l;
}

// Gaussian smearing: rbf[e][g] (g padded to 64), hi/lo fp16
__global__ void conv_rbf(const float* __restrict__ dist, _Float16* __restrict__ rhi,
                         _Float16* __restrict__ rlo) {
    int idx = blockIdx.x * 256 + threadIdx.x;  // E*64
    if (idx >= E_EDGES * 64) return;
    int e = idx >> 6, g = idx & 63;
    const float step = 12.0f / 49.0f;
    const float coeff = -0.5f / (step * step);
    float v = 0.0f;
    if (g < NGAUSS) {
        float t = dist[e] - (float)g * step;
        v = __expf(coeff * t * t);
    }
    _Float16 hh = (_Float16)v;
    rhi[idx] = hh;
    rlo[idx] = (_Float16)(v - (float)hh);
}

// ---------------------------------------------------------------------------
// MFMA GEMM, 128x128 tile, 4 waves (2x2 of 64x64), K-step 32.
// MODE 1: A = hi/lo gather [x[src]|x[dst]|x[edge]] (K=1536, 3-pass),
//         epi: gelu -> h (SINGLE fp16 plane)
// MODE 2: A = h single-plane (K=1024, 2-pass), B = Wres hi/lo,
//         epi: h2 = h + gelu(acc+b)  (separate buffer -> NO in-place race)
// MODE 3: A = h2 single-plane (K=1024, 2-pass) + rbf hi/lo pre-pass (K=64,
//         3-pass), epi: ((acc+bout)*Wfin).racc reduce -> partial
// A-staging lane remap (R6): lane = piece*16 + rowg -> 64B-line coalesced.
// Grid: blockIdx.x = n-block (fast) so A-panel sharers are dispatch-adjacent.
// ---------------------------------------------------------------------------
template <int MODE>
__global__ __launch_bounds__(256, 2) void gemm_k(
    const _Float16* __restrict__ Ahi, const _Float16* __restrict__ Alo,
    const _Float16* __restrict__ Bhi, const _Float16* __restrict__ Blo,
    const int* __restrict__ ei, const float* __restrict__ bias,
    _Float16* __restrict__ outHi,
    const _Float16* __restrict__ rbfHi, const _Float16* __restrict__ rbfLo,
    const _Float16* __restrict__ WrbHi, const _Float16* __restrict__ WrbLo,
    const float* __restrict__ Wfin, float* __restrict__ partial,
    int Ktiles, int N)
{
    __shared__ __align__(16) _Float16 sA[2][8][4][16][8];  // [pl][grp][piece][row16][8]
    __shared__ __align__(16) _Float16 sB[2][4][128][8];    // [pl][kc][col][8]
    __shared__ float red[128][2];

    const int tid = threadIdx.x;
    const int lane = tid & 63;
    const int wid = tid >> 6;
    const int fr = lane & 15;
    const int kq = lane >> 4;
    const int wr = (wid >> 1) * 64;
    const int wc = (wid & 1) * 64;
    const int e0 = blockIdx.y * 128;
    const int n0 = blockIdx.x * 128;

    _Float16* sAb = &sA[0][0][0][0][0];
    _Float16* sBb = &sB[0][0][0][0];

    const int rowg = lane & 15;
    const int piece = lane >> 4;

    // ---- A staging setup: MODE 1: 16 issues (4/wave, 2 planes x 8 grps);
    //      MODE 2/3 main loop: 8 issues (2/wave, single plane x 8 grps) ----
    constexpr int NA = (MODE == 1) ? 4 : 2;
    int aplA[NA], agrpA[NA];
    int nsrcA[NA], ndstA[NA], nedgA[NA];
    const _Float16* aPtr[NA];
#pragma unroll
    for (int i = 0; i < NA; ++i) {
        int idx = wid * NA + i;
        int apl  = (MODE == 1) ? (idx >> 3) : 0;
        int agrp = (MODE == 1) ? (idx & 7) : idx;
        aplA[i] = apl; agrpA[i] = agrp;
        int er = e0 + agrp * 16 + rowg;
        if (er >= E_EDGES) er = E_EDGES - 1;
        if constexpr (MODE == 1) {
            nsrcA[i] = ei[er];
            ndstA[i] = ei[E_EDGES + er];
            nedgA[i] = NNODES + er;
        } else {
            aPtr[i] = Ahi + (size_t)er * FF + piece * 8;
        }
    }

    // ---- B staging setup: 2 issues per wave per plane ----
    int cwB[2], nB[2];
#pragma unroll
    for (int iss = 0; iss < 2; ++iss) {
        int cwv = (wid * 2 + iss) * 64;
        cwB[iss] = cwv;
        nB[iss] = (cwv & 127) + lane;
    }

    float4v acc[4][4];
    float4v racc[4][4];
#pragma unroll
    for (int i = 0; i < 4; ++i)
#pragma unroll
        for (int j = 0; j < 4; ++j) {
            acc[i][j] = (float4v){0.f, 0.f, 0.f, 0.f};
            racc[i][j] = (float4v){0.f, 0.f, 0.f, 0.f};
        }

    // ---- MODE 3: rbf-projection pre-pass (hi/lo, 3-pass, 2 K-tiles) ----
    if constexpr (MODE == 3) {
        int rapl[4], ragrp[4];
        const _Float16* rPtr[4];
#pragma unroll
        for (int i = 0; i < 4; ++i) {
            int idx = wid * 4 + i;
            rapl[i] = idx >> 3; ragrp[i] = idx & 7;
            int er = e0 + ragrp[i] * 16 + rowg;
            if (er >= E_EDGES) er = E_EDGES - 1;
            rPtr[i] = (rapl[i] ? rbfLo : rbfHi) + (size_t)er * 64 + piece * 8;
        }
        for (int kt = 0; kt < 2; ++kt) {
            int k0 = kt * 32;
#pragma unroll
            for (int i = 0; i < 4; ++i)
                gload16(rPtr[i] + k0, sAb + (size_t)(rapl[i] * 8 + ragrp[i]) * 512);
#pragma unroll
            for (int iss = 0; iss < 2; ++iss) {
                size_t bo = ((size_t)(kt * 4 + (cwB[iss] >> 7)) * N + n0 + nB[iss]) * 8;
                gload16(WrbHi + bo, sBb + cwB[iss] * 8);
                gload16(WrbLo + bo, sBb + 4096 + cwB[iss] * 8);
            }
            __syncthreads();
            half8 ah[4], al[4], bh[4], bl[4];
#pragma unroll
            for (int f = 0; f < 4; ++f) {
                ah[f] = *(const half8*)&sA[0][(wr >> 4) + f][kq][fr][0];
                al[f] = *(const half8*)&sA[1][(wr >> 4) + f][kq][fr][0];
                int cc = wc + f * 16 + fr;
                bh[f] = *(const half8*)&sB[0][kq][cc][0];
                bl[f] = *(const half8*)&sB[1][kq][cc][0];
            }
#pragma unroll
            for (int fi = 0; fi < 4; ++fi)
#pragma unroll
                for (int fj = 0; fj < 4; ++fj) {
                    racc[fi][fj] = __builtin_amdgcn_mfma_f32_16x16x32_f16(ah[fi], bh[fj], racc[fi][fj], 0, 0, 0);
                    racc[fi][fj] = __builtin_amdgcn_mfma_f32_16x16x32_f16(ah[fi], bl[fj], racc[fi][fj], 0, 0, 0);
                    racc[fi][fj] = __builtin_amdgcn_mfma_f32_16x16x32_f16(al[fi], bh[fj], racc[fi][fj], 0, 0, 0);
                }
            __syncthreads();
        }
    }

    // ---- main K loop ----
    for (int kt = 0; kt < Ktiles; ++kt) {
        int k0 = kt * 32;
        if constexpr (MODE == 1) {
            int sec = k0 >> 9;                       // wave-uniform section
            int ks = (k0 & 511) + piece * 8;
#pragma unroll
            for (int i = 0; i < 4; ++i) {
                int node = (sec == 0) ? nsrcA[i] : (sec == 1) ? ndstA[i] : nedgA[i];
                const _Float16* s = (aplA[i] ? Alo : Ahi) + (size_t)node * EMBED + ks;
                gload16(s, sAb + (size_t)(aplA[i] * 8 + agrpA[i]) * 512);
            }
        } else {
#pragma unroll
            for (int i = 0; i < 2; ++i)
                gload16(aPtr[i] + k0, sAb + (size_t)agrpA[i] * 512);
        }
#pragma unroll
        for (int iss = 0; iss < 2; ++iss) {
            size_t bo = ((size_t)(kt * 4 + (cwB[iss] >> 7)) * N + n0 + nB[iss]) * 8;
            gload16(Bhi + bo, sBb + cwB[iss] * 8);
            gload16(Blo + bo, sBb + 4096 + cwB[iss] * 8);
        }
        __syncthreads();
        half8 ah[4], al[4], bh[4], bl[4];
#pragma unroll
        for (int f = 0; f < 4; ++f) {
            ah[f] = *(const half8*)&sA[0][(wr >> 4) + f][kq][fr][0];
            if constexpr (MODE == 1)
                al[f] = *(const half8*)&sA[1][(wr >> 4) + f][kq][fr][0];
            int cc = wc + f * 16 + fr;
            bh[f] = *(const half8*)&sB[0][kq][cc][0];
            bl[f] = *(const half8*)&sB[1][kq][cc][0];
        }
#pragma unroll
        for (int fi = 0; fi < 4; ++fi)
#pragma unroll
            for (int fj = 0; fj < 4; ++fj) {
                acc[fi][fj] = __builtin_amdgcn_mfma_f32_16x16x32_f16(ah[fi], bh[fj], acc[fi][fj], 0, 0, 0);
                acc[fi][fj] = __builtin_amdgcn_mfma_f32_16x16x32_f16(ah[fi], bl[fj], acc[fi][fj], 0, 0, 0);
                if constexpr (MODE == 1)
                    acc[fi][fj] = __builtin_amdgcn_mfma_f32_16x16x32_f16(al[fi], bh[fj], acc[fi][fj], 0, 0, 0);
            }
        __syncthreads();
    }

    // ---- epilogues ----
    if constexpr (MODE == 1) {
#pragma unroll
        for (int fj = 0; fj < 4; ++fj) {
            int col = n0 + wc + fj * 16 + fr;
            float bo = bias[col];
#pragma unroll
            for (int fi = 0; fi < 4; ++fi) {
                int rowb = e0 + wr + fi * 16 + 4 * kq;
#pragma unroll
                for (int i = 0; i < 4; ++i) {
                    int row = rowb + i;
                    if (row < E_EDGES)
                        outHi[(size_t)row * FF + col] = (_Float16)gelu_f(acc[fi][fj][i] + bo);
                }
            }
        }
    } else if constexpr (MODE == 2) {
#pragma unroll
        for (int fj = 0; fj < 4; ++fj) {
            int col = n0 + wc + fj * 16 + fr;
            float bo = bias[col];
#pragma unroll
            for (int fi = 0; fi < 4; ++fi) {
                int rowb = e0 + wr + fi * 16 + 4 * kq;
#pragma unroll
                for (int i = 0; i < 4; ++i) {
                    int row = rowb + i;
                    if (row < E_EDGES) {
                        size_t o = (size_t)row * FF + col;
                        outHi[o] = (_Float16)((float)Ahi[o] + gelu_f(acc[fi][fj][i] + bo));
                    }
                }
            }
        }
    } else {
        float rs[4][4];
#pragma unroll
        for (int fi = 0; fi < 4; ++fi)
#pragma unroll
            for (int i = 0; i < 4; ++i) rs[fi][i] = 0.0f;
#pragma unroll
        for (int fj = 0; fj < 4; ++fj) {
            int col = n0 + wc + fj * 16 + fr;
            float wf = Wfin[col];
            float bo = bias[col];
#pragma unroll
            for (int fi = 0; fi < 4; ++fi)
#pragma unroll
                for (int i = 0; i < 4; ++i)
                    rs[fi][i] += (acc[fi][fj][i] + bo) * wf * racc[fi][fj][i];
        }
#pragma unroll
        for (int fi = 0; fi < 4; ++fi)
#pragma unroll
            for (int i = 0; i < 4; ++i) {
                float s = rs[fi][i];
                s += __shfl_xor(s, 1, 64);
                s += __shfl_xor(s, 2, 64);
                s += __shfl_xor(s, 4, 64);
                s += __shfl_xor(s, 8, 64);
                if (fr == 0) red[wr + fi * 16 + 4 * kq + i][wid & 1] = s;
            }
        __syncthreads();
        if (tid < 128) {
            int e = e0 + tid;
            if (e < E_EDGES) atomicAdd(&partial[e], red[tid][0] + red[tid][1]);
        }
    }
}

// ---------------------------------------------------------------------------
// Finalize: energy = segsum(pe by batch[src]); forces = segsum(pf*vec by src)
// ---------------------------------------------------------------------------
__global__ void finalize(const float* __restrict__ pe, const float* __restrict__ pf,
                         const int* __restrict__ ei, const int* __restrict__ batch,
                         const float* __restrict__ vec_hat,
                         float* __restrict__ energy, float* __restrict__ forces) {
    __shared__ float bins[NGRAPHS];
    int t = blockIdx.x * 256 + threadIdx.x;
    if (threadIdx.x < NGRAPHS) bins[threadIdx.x] = 0.0f;
    __syncthreads();
    if (t < E_EDGES) {
        int s = ei[t];
        atomicAdd(&bins[batch[s]], pe[t]);
        float sf = pf[t];
        atomicAdd(&forces[s * 3 + 0], sf * vec_hat[t * 3 + 0]);
        atomicAdd(&forces[s * 3 + 1], sf * vec_hat[t * 3 + 1]);
        atomicAdd(&forces[s * 3 + 2], sf * vec_hat[t * 3 + 2]);
    }
    __syncthreads();
    if (threadIdx.x < NGRAPHS) atomicAdd(&energy[threadIdx.x], bins[threadIdx.x]);
}

// ---------------------------------------------------------------------------
extern "C" void kernel_launch(void* const* d_in, const int* in_sizes, int n_in,
                              void* d_out, int out_size, void* d_ws, size_t ws_size,
                              hipStream_t stream)
{
    (void)in_sizes; (void)n_in; (void)ws_size;

    const float* x       = (const float*)d_in[0];
    const float* dist    = (const float*)d_in[2];
    const float* vec_hat = (const float*)d_in[3];
    const int*   batch   = (const int*)d_in[4];
    const int*   ei      = (const int*)d_in[5];
    const float* e_Win   = (const float*)d_in[6];
    const float* e_bin   = (const float*)d_in[7];
    const float* e_Wres  = (const float*)d_in[8];
    const float* e_bres  = (const float*)d_in[9];
    const float* e_Wout  = (const float*)d_in[10];
    const float* e_bout  = (const float*)d_in[11];
    const float* e_Wrbf  = (const float*)d_in[12];
    const float* e_Wfin  = (const float*)d_in[13];
    const float* f_Win   = (const float*)d_in[14];
    const float* f_bin   = (const float*)d_in[15];
    const float* f_Wres  = (const float*)d_in[16];
    const float* f_bres  = (const float*)d_in[17];
    const float* f_Wout  = (const float*)d_in[18];
    const float* f_bout  = (const float*)d_in[19];
    const float* f_Wrbf  = (const float*)d_in[20];
    const float* f_Wfin  = (const float*)d_in[21];

    float* out = (float*)d_out;

    // ws layout (~687 MB total — same footprint as the R8 proven layout)
    char* w = (char*)d_ws;
    size_t off = 0;
    auto alloc = [&](size_t bytes) -> void* {
        void* p = w + off;
        off += (bytes + 255) & ~(size_t)255;
        return p;
    };
    const size_t NX = (size_t)(NNODES + E_EDGES) * EMBED;      // 56,320,000
    _Float16* xhi = (_Float16*)alloc(NX * 2);
    _Float16* xlo = (_Float16*)alloc(NX * 2);
    _Float16* h   = (_Float16*)alloc((size_t)E_EDGES * FF * 2);   // single plane
    _Float16* h2  = (_Float16*)alloc((size_t)E_EDGES * FF * 2);   // single plane
    _Float16* rbfHi = (_Float16*)alloc((size_t)E_EDGES * 64 * 2);
    _Float16* rbfLo = (_Float16*)alloc((size_t)E_EDGES * 64 * 2);
    _Float16 *WinH[2], *WinL[2], *WresH[2], *WresL[2], *WoutH[2], *WoutL[2], *WrbH[2], *WrbL[2];
    for (int b = 0; b < 2; ++b) {
        WinH[b]  = (_Float16*)alloc((size_t)1536 * 1024 * 2);
        WinL[b]  = (_Float16*)alloc((size_t)1536 * 1024 * 2);
        WresH[b] = (_Float16*)alloc((size_t)1024 * 1024 * 2);
        WresL[b] = (_Float16*)alloc((size_t)1024 * 1024 * 2);
        WoutH[b] = (_Float16*)alloc((size_t)1024 * 512 * 2);
        WoutL[b] = (_Float16*)alloc((size_t)1024 * 512 * 2);
        WrbH[b]  = (_Float16*)alloc((size_t)64 * 512 * 2);
        WrbL[b]  = (_Float16*)alloc((size_t)64 * 512 * 2);
    }
    float* pe = (float*)alloc((size_t)E_EDGES * 4);
    float* pf = (float*)alloc((size_t)E_EDGES * 4);

    hipMemsetAsync(d_out, 0, sizeof(float) * (size_t)out_size, stream);
    hipMemsetAsync(pe, 0, (size_t)E_EDGES * 4, stream);
    hipMemsetAsync(pf, 0, (size_t)E_EDGES * 4, stream);

    // prep
    conv_x<<<55000, 256, 0, stream>>>(x, xhi, xlo, NX / 4);
    conv_rbf<<<25000, 256, 0, stream>>>(dist, rbfHi, rbfLo);
    conv_w<<<768, 256, 0, stream>>>(e_Win, WinH[0], WinL[0], 196608, 10, 1023);
    conv_w<<<768, 256, 0, stream>>>(f_Win, WinH[1], WinL[1], 196608, 10, 1023);
    conv_w<<<512, 256, 0, stream>>>(e_Wres, WresH[0], WresL[0], 131072, 10, 1023);
    conv_w<<<512, 256, 0, stream>>>(f_Wres, WresH[1], WresL[1], 131072, 10, 1023);
    conv_w<<<256, 256, 0, stream>>>(e_Wout, WoutH[0], WoutL[0], 65536, 9, 511);
    conv_w<<<256, 256, 0, stream>>>(f_Wout, WoutH[1], WoutL[1], 65536, 9, 511);
    conv_wrbf<<<16, 256, 0, stream>>>(e_Wrbf, WrbH[0], WrbL[0]);
    conv_wrbf<<<16, 256, 0, stream>>>(f_Wrbf, WrbH[1], WrbL[1]);

    const int MB = (E_EDGES + 127) / 128;  // 782
    const float* bin_[2]  = {e_bin, f_bin};
    const float* bres_[2] = {e_bres, f_bres};
    const float* bout_[2] = {e_bout, f_bout};
    const float* wfin_[2] = {e_Wfin, f_Wfin};
    float* part_[2] = {pe, pf};

    for (int b = 0; b < 2; ++b) {
        gemm_k<1><<<dim3(8, MB), 256, 0, stream>>>(
            xhi, xlo, WinH[b], WinL[b], ei, bin_[b], h,
            nullptr, nullptr, nullptr, nullptr, nullptr, nullptr, 48, FF);
        gemm_k<2><<<dim3(8, MB), 256, 0, stream>>>(
            h, nullptr, WresH[b], WresL[b], nullptr, bres_[b], h2,
            nullptr, nullptr, nullptr, nullptr, nullptr, nullptr, 32, FF);
        gemm_k<3><<<dim3(4, MB), 256, 0, stream>>>(
            h2, nullptr, WoutH[b], WoutL[b], nullptr, bout_[b], nullptr,
            rbfHi, rbfLo, WrbH[b], WrbL[b], wfin_[b], part_[b], 32, EMBED);
    }

    finalize<<<(E_EDGES + 255) / 256, 256, 0, stream>>>(pe, pf, ei, batch, vec_hat, out, out + NGRAPHS);
}